// Round 13
// baseline (106.460 us; speedup 1.0000x reference)
//
#include <hip/hip_runtime.h>
#include <hip/hip_fp16.h>

// Multi-scale deformable attention forward, MI355X.
// value: (2, 19947, 8, 32) f32 ; loc: (2, 19947, 8, 4, 4, 2) f32
// attw:  (2, 19947, 8, 4, 4) f32 ; out: (2, 19947, 256) f32
// R3: value transposed to (b,h,key,32ch) f16; (b,h) pinned to XCD (pair=blk&15).
// R4: packed-fp16 accumulation; x-weight via distance form max(0,1-|x-k|).
// R7: asm gather pipeline, counted vmcnt + sched_barrier, 16-24 in flight.
// R10: lane-dedup addr math + __shfl broadcast.
// R12: x-pair-DUPLICATED 128B-aligned layout for levels 0+1 (the L1-missing
// 75% of gather traffic): entry(y,x) = [key x | key x+1], so every row access
// is exactly ONE cache line (was 1.5 avg). 2x storage for l0+l1 -> ws 39.3MB;
// falls back to R10 plain layout (20.4MB) then f32.
// LESSON (R9): keep launch_bounds loose; scratch spills corrupt manual vmcnt.
// LESSON (R11): not VALU-bound -- only byte/line reduction moves the needle.

#define KQ 19947
#define NBQ (2 * KQ)

// dup layout, units = halves, per pair:
//   dupL0 @ 0       : 100 rows x 149 entries x 64  = 953600
//   dupL1 @ 953600  :  50 rows x  74 entries x 64  = 236800
//   L2    @ 1190400 : 950 keys x 32                =  30400
//   L3    @ 1220800 : 247 keys x 32                =   7904
#define PAIR_HALVES 1228704

// ---------- pack 8 f32 -> 8 f16 (16B) ----------
static __device__ __forceinline__ uint4 pack8(const float* __restrict__ src) {
    const float4 a0 = *reinterpret_cast<const float4*>(src);
    const float4 a1 = *reinterpret_cast<const float4*>(src + 4);
    __half2 h0 = __floats2half2_rn(a0.x, a0.y);
    __half2 h1 = __floats2half2_rn(a0.z, a0.w);
    __half2 h2 = __floats2half2_rn(a1.x, a1.y);
    __half2 h3 = __floats2half2_rn(a1.z, a1.w);
    uint4 o;
    o.x = *reinterpret_cast<unsigned int*>(&h0);
    o.y = *reinterpret_cast<unsigned int*>(&h1);
    o.z = *reinterpret_cast<unsigned int*>(&h2);
    o.w = *reinterpret_cast<unsigned int*>(&h3);
    return o;
}

// ---------- transpose variants ----------
__global__ __launch_bounds__(256) void transpose_f16(
    const float* __restrict__ V, __half* __restrict__ Vh)
{
    const int pair = blockIdx.y;                    // b*8+h
    const int j = blockIdx.x * 256 + threadIdx.x;   // (k, cg)
    if (j >= KQ * 4) return;
    const int k = j >> 2, cg = j & 3;
    const int b = pair >> 3, h = pair & 7;
    const uint4 o = pack8(V + (((size_t)b * KQ + k) * 8 + h) * 32 + cg * 8);
    reinterpret_cast<uint4*>(Vh + ((size_t)pair * KQ) * 32)[j] = o;
}

__global__ __launch_bounds__(256) void transpose_dup(
    const float* __restrict__ V, __half* __restrict__ Vh)
{
    const int pair = blockIdx.y;
    const int j = blockIdx.x * 256 + threadIdx.x;
    if (j >= KQ * 4) return;
    const int k = j >> 2, cg = j & 3;
    const int b = pair >> 3, h = pair & 7;
    const uint4 o = pack8(V + (((size_t)b * KQ + k) * 8 + h) * 32 + cg * 8);
    __half* base = Vh + (size_t)pair * PAIR_HALVES;
    int dst0 = -1, dst1 = -1;                       // in halves
    if (k < 15000) {                                // level 0: 100 x 150
        const int y = k / 150, x = k - y * 150;
        if (x <= 148) dst0 = (y * 149 + x) * 64 + cg * 8;
        if (x >= 1)   dst1 = (y * 149 + x - 1) * 64 + 32 + cg * 8;
    } else if (k < 18750) {                         // level 1: 50 x 75
        const int kk = k - 15000;
        const int y = kk / 75, x = kk - y * 75;
        if (x <= 73) dst0 = 953600 + (y * 74 + x) * 64 + cg * 8;
        if (x >= 1)  dst1 = 953600 + (y * 74 + x - 1) * 64 + 32 + cg * 8;
    } else if (k < 19700) {                         // level 2 plain
        dst0 = 1190400 + (k - 18750) * 32 + cg * 8;
    } else {                                        // level 3 plain
        dst0 = 1220800 + (k - 19700) * 32 + cg * 8;
    }
    if (dst0 >= 0) *reinterpret_cast<uint4*>(base + dst0) = o;
    if (dst1 >= 0) *reinterpret_cast<uint4*>(base + dst1) = o;
}

// ---------- shared (slot-invariant) point math ----------
// Lane j handles point pt = j + 8*ROUND; level = 2*ROUND + (j>>2).
// DUP: dup layout for ROUND 0 (levels 0,1), plain for ROUND 1 (levels 2,3).
template<int ROUND, bool DUP>
static __device__ __forceinline__ void shared_point(
    int j, float2 g, float w,
    int& offb0, int& offb1, float& dxx, float& wy0w, float& wy1w)
{
    const bool hi = (j & 4) != 0;
    const int Wl = (ROUND == 0) ? (hi ? 75 : 150) : (hi ? 19 : 38);
    const int Hl = (ROUND == 0) ? (hi ? 50 : 100) : (hi ? 13 : 25);
    const float Wf = (float)Wl, Hf = (float)Hl;
    const float x = fmaf(g.x, Wf, -0.5f);
    const float y = fmaf(g.y, Hf, -0.5f);
    const float fy = floorf(y);
    const int y0 = (int)fy;
    const int x0 = (int)floorf(x);
    const int bx = min(max(x0, 0), Wl - 2);
    dxx = x - (float)bx;                 // consumer: wxl = max(0,1-|dxx-slot|)
    const float wy1 = y - fy, wy0 = 1.f - wy1;
    const int y0c = max(y0, 0);
    const int y1c = min(y0 + 1, Hl - 1);
    const float ay0 = (y0 >= 0) ? wy0 : 0.f;
    const float ay1 = (y0 + 1 < Hl) ? wy1 : 0.f;
    wy0w = w * ay0;
    wy1w = w * ay1;
    if (DUP) {
        if (ROUND == 0) {                // dup entries, 64 halves each
            const int stride = Wl - 1;
            const int baseH = hi ? 953600 : 0;
            offb0 = baseH + ((y0c * stride + bx) << 6);
            offb1 = baseH + ((y1c * stride + bx) << 6);
        } else {                         // plain keys, 32 halves each
            const int baseH = hi ? 1220800 : 1190400;
            offb0 = baseH + ((y0c * Wl + bx) << 5);
            offb1 = baseH + ((y1c * Wl + bx) << 5);
        }
    } else {
        const int st = (ROUND == 0) ? (hi ? 15000 : 0) : (hi ? 19700 : 18750);
        offb0 = (st + y0c * Wl + bx) << 5;
        offb1 = (st + y1c * Wl + bx) << 5;
    }
}

static __device__ __forceinline__ void consume_level(
    const uint4* v, const float* cw, float acc[8])
{
    __half2 accH[4];
    #pragma unroll
    for (int j = 0; j < 4; ++j) accH[j] = __half2(__half(0.f), __half(0.f));
    #pragma unroll
    for (int i = 0; i < 8; ++i) {
        const __half2 wh = __floats2half2_rn(cw[i], cw[i]);
        union { uint4 u; __half2 h2[4]; } uv;
        uv.u = v[i];
        #pragma unroll
        for (int j = 0; j < 4; ++j)
            accH[j] = __hfma2(wh, uv.h2[j], accH[j]);
    }
    #pragma unroll
    for (int j = 0; j < 4; ++j) {
        const float2 f = __half22float2(accH[j]);
        acc[2*j]   += f.x;
        acc[2*j+1] += f.y;
    }
}

#define GLOAD8(buf, obase)                                                   \
    {                                                                        \
        _Pragma("unroll")                                                    \
        for (int i = 0; i < 8; ++i) {                                        \
            const __half* p_ = vbl + (obase)[i];                             \
            asm volatile("global_load_dwordx4 %0, %1, off"                   \
                         : "=v"(buf[i]) : "v"(p_));                          \
        }                                                                    \
    }
#define VWAIT(n)                                                             \
    asm volatile("s_waitcnt vmcnt(" #n ")" ::: "memory");                    \
    __builtin_amdgcn_sched_barrier(0)
#define SBAR() __builtin_amdgcn_sched_barrier(0)

// ---------- gather: block = one (b,h) x 32 queries; 8 lanes per query ----------
template<bool DUP>
__global__ __launch_bounds__(256, 3) void msda_fwd_t(
    const __half* __restrict__ Vh,
    const float* __restrict__ LOC,
    const float* __restrict__ W,
    float* __restrict__ OUT)
{
    const int pair = blockIdx.x & 15;               // b*8+h -> XCD = blk % 8
    const int qc   = blockIdx.x >> 4;
    const int tid  = threadIdx.x;
    const int s    = tid & 7;                       // slot = s>>2, chgrp = s&3
    const int slot = s >> 2;
    const float slotf = (float)slot;
    const int q    = qc * 32 + (tid >> 3);
    if (q >= KQ) return;
    const int b = pair >> 3, h = pair & 7;
    const int ln = tid & 63;
    const int gb = ln & 56;                         // query-group base lane

    const size_t pairBase = DUP ? ((size_t)pair * PAIR_HALVES)
                                : ((size_t)pair * KQ * 32);
    const __half* vbl = Vh + pairBase + s * 8;
    const float* lp = LOC + (((size_t)b * KQ + q) * 8 + h) * 32;
    const float* wp = W   + (((size_t)b * KQ + q) * 8 + h) * 16;

    float acc[8];
    #pragma unroll
    for (int c = 0; c < 8; ++c) acc[c] = 0.f;

    // ---- dedup addr math: lane j computes points j and j+8 once ----
    const float2 gA = *reinterpret_cast<const float2*>(lp + 2 * s);
    const float  wA = wp[s];
    const float2 gB = *reinterpret_cast<const float2*>(lp + 2 * s + 16);
    const float  wB = wp[s + 8];

    int ob0A, ob1A, ob0B, ob1B;
    float dxA, u0A, u1A, dxB, u0B, u1B;
    shared_point<0, DUP>(s, gA, wA, ob0A, ob1A, dxA, u0A, u1A);
    shared_point<1, DUP>(s, gB, wB, ob0B, ob1B, dxB, u0B, u1B);

    // ---- broadcast + per-slot finish: off/cw for all 16 points ----
    int off[32];
    float cw[32];
    #pragma unroll
    for (int pt = 0; pt < 8; ++pt) {                // points 0..7 (levels 0,1)
        const int src = gb + pt;
        const int   o0 = __shfl(ob0A, src, 64);
        const int   o1 = __shfl(ob1A, src, 64);
        const float dx = __shfl(dxA,  src, 64);
        const float u0 = __shfl(u0A,  src, 64);
        const float u1 = __shfl(u1A,  src, 64);
        const float wxl = fmaxf(0.f, 1.f - fabsf(dx - slotf));
        off[2*pt]   = o0;
        off[2*pt+1] = o1;
        cw[2*pt]    = u0 * wxl;
        cw[2*pt+1]  = u1 * wxl;
    }
    #pragma unroll
    for (int pt = 0; pt < 8; ++pt) {                // points 8..15 (levels 2,3)
        const int src = gb + pt;
        const int   o0 = __shfl(ob0B, src, 64);
        const int   o1 = __shfl(ob1B, src, 64);
        const float dx = __shfl(dxB,  src, 64);
        const float u0 = __shfl(u0B,  src, 64);
        const float u1 = __shfl(u1B,  src, 64);
        const float wxl = fmaxf(0.f, 1.f - fabsf(dx - slotf));
        off[16+2*pt]   = o0;
        off[16+2*pt+1] = o1;
        cw[16+2*pt]    = u0 * wxl;
        cw[16+2*pt+1]  = u1 * wxl;
    }

    // drain compiler-issued vmem (loc/attw) so manual vmcnt counts are exact
    VWAIT(0);

    uint4 va[8], vb2[8], vc[8];
    GLOAD8(va,  off + 0);                 // l0: 8 outstanding
    GLOAD8(vb2, off + 8);                 // l1: 16 outstanding
    VWAIT(8);                             // l0 ready
    GLOAD8(vc,  off + 16);                // l2: 16 outstanding
    SBAR();
    consume_level(va, cw + 0, acc);       // level 0
    SBAR();                               // pin consume before va reuse
    GLOAD8(va,  off + 24);                // l3: <= 24 outstanding
    VWAIT(16);                            // l1 ready (l2, l3 in flight)
    consume_level(vb2, cw + 8, acc);      // level 1
    VWAIT(8);                             // l2 ready
    consume_level(vc, cw + 16, acc);      // level 2
    VWAIT(0);                             // l3 ready
    consume_level(va, cw + 24, acc);      // level 3

    // combine the two key-slots: lanes s and s^4 hold the two x-corners
    #pragma unroll
    for (int c = 0; c < 8; ++c)
        acc[c] += __shfl_xor(acc[c], 4, 64);

    // lane s writes channels chgrp*8 + slot*4 .. +4
    float* op = OUT + ((size_t)b * KQ + q) * 256 + h * 32 + (s & 3) * 8 + slot * 4;
    *reinterpret_cast<float4*>(op) =
        make_float4(acc[slot*4], acc[slot*4+1], acc[slot*4+2], acc[slot*4+3]);
}

// ---------- f32 fallback (no workspace needed) ----------
static __device__ __forceinline__ void fmadd4(float4& a, float s, const float4 v) {
    a.x = fmaf(s, v.x, a.x);
    a.y = fmaf(s, v.y, a.y);
    a.z = fmaf(s, v.z, a.z);
    a.w = fmaf(s, v.w, a.w);
}

__global__ __launch_bounds__(256, 4) void msda_fwd_f32(
    const float* __restrict__ V,
    const float* __restrict__ LOC,
    const float* __restrict__ W,
    float* __restrict__ OUT)
{
    const int t  = blockIdx.x * 256 + threadIdx.x;
    const int cg = t & 7;
    const int h  = (t >> 3) & 7;
    const int bq = t >> 6;
    if (bq >= NBQ) return;
    const int b = (bq >= KQ) ? 1 : 0;

    const int Hs[4]  = {100, 50, 25, 13};
    const int Ws[4]  = {150, 75, 38, 19};
    const int STs[4] = {0, 15000, 18750, 19700};

    const int hoff = (h << 5) + (cg << 2);
    const float* vb = V + (size_t)b * KQ * 256 + hoff;
    const float* lp = LOC + ((size_t)bq * 8 + h) * 32;
    const float* wp = W   + ((size_t)bq * 8 + h) * 16;

    float4 acc = make_float4(0.f, 0.f, 0.f, 0.f);

    #pragma unroll
    for (int l = 0; l < 4; ++l) {
        const int Hh = Hs[l], Ww = Ws[l], st = STs[l];
        const float Hf = (float)Hh, Wf = (float)Ww;
        const float4 w4 = *reinterpret_cast<const float4*>(wp + l * 4);
        const float4 g0 = *reinterpret_cast<const float4*>(lp + l * 8);
        const float4 g1 = *reinterpret_cast<const float4*>(lp + l * 8 + 4);
        const float lx[4] = {g0.x, g0.z, g1.x, g1.z};
        const float ly[4] = {g0.y, g0.w, g1.y, g1.w};
        const float ww[4] = {w4.x, w4.y, w4.z, w4.w};
        #pragma unroll
        for (int p = 0; p < 4; ++p) {
            const float x = fmaf(lx[p], Wf, -0.5f);
            const float y = fmaf(ly[p], Hf, -0.5f);
            const float fx = floorf(x), fy = floorf(y);
            const int x0 = (int)fx, y0 = (int)fy;
            const float wx1 = x - fx, wy1 = y - fy;
            const float wx0 = 1.f - wx1, wy0 = 1.f - wy1;
            const int x0c = max(x0, 0),     x1c = min(x0 + 1, Ww - 1);
            const int y0c = max(y0, 0),     y1c = min(y0 + 1, Hh - 1);
            const float ax0 = (x0 >= 0)      ? wx0 : 0.f;
            const float ax1 = (x0 + 1 < Ww)  ? wx1 : 0.f;
            const float ay0 = (y0 >= 0)      ? wy0 : 0.f;
            const float ay1 = (y0 + 1 < Hh)  ? wy1 : 0.f;
            const float w = ww[p];
            const int b0 = st + y0c * Ww, b1 = st + y1c * Ww;
            fmadd4(acc, w*ay0*ax0, *reinterpret_cast<const float4*>(vb + ((b0+x0c) << 8)));
            fmadd4(acc, w*ay0*ax1, *reinterpret_cast<const float4*>(vb + ((b0+x1c) << 8)));
            fmadd4(acc, w*ay1*ax0, *reinterpret_cast<const float4*>(vb + ((b1+x0c) << 8)));
            fmadd4(acc, w*ay1*ax1, *reinterpret_cast<const float4*>(vb + ((b1+x1c) << 8)));
        }
    }
    *reinterpret_cast<float4*>(OUT + (size_t)bq * 256 + hoff) = acc;
}

extern "C" void kernel_launch(void* const* d_in, const int* in_sizes, int n_in,
                              void* d_out, int out_size, void* d_ws, size_t ws_size,
                              hipStream_t stream) {
    const float* V   = (const float*)d_in[0];
    const float* LOC = (const float*)d_in[2];
    const float* W   = (const float*)d_in[3];
    float* OUT = (float*)d_out;

    const size_t need_dup   = (size_t)16 * PAIR_HALVES * 2 + 256;  // ~39.3 MB
    const size_t need_plain = (size_t)2 * KQ * 256 * 2 + 256;      // ~20.4 MB
    const int jtot = KQ * 4;
    const int qchunks = (KQ + 31) / 32;             // 624
    const int gblocks = qchunks * 16;               // 9984

    if (ws_size >= need_dup) {
        __half* Vh = (__half*)d_ws;
        dim3 tgrid((jtot + 255) / 256, 16);
        hipLaunchKernelGGL(transpose_dup, tgrid, dim3(256), 0, stream, V, Vh);
        hipLaunchKernelGGL((msda_fwd_t<true>), dim3(gblocks), dim3(256), 0, stream,
                           Vh, LOC, W, OUT);
    } else if (ws_size >= need_plain) {
        __half* Vh = (__half*)d_ws;
        dim3 tgrid((jtot + 255) / 256, 16);
        hipLaunchKernelGGL(transpose_f16, tgrid, dim3(256), 0, stream, V, Vh);
        hipLaunchKernelGGL((msda_fwd_t<false>), dim3(gblocks), dim3(256), 0, stream,
                           Vh, LOC, W, OUT);
    } else {
        const int total = NBQ * 64;
        hipLaunchKernelGGL(msda_fwd_f32, dim3((total + 255) / 256), dim3(256), 0, stream,
                           V, LOC, W, OUT);
    }
}

// Round 14
// 84.225 us; speedup vs baseline: 1.2640x; 1.2640x over previous
//
#include <hip/hip_runtime.h>
#include <hip/hip_fp16.h>

// Multi-scale deformable attention forward, MI355X.
// value: (2, 19947, 8, 32) f32 ; loc: (2, 19947, 8, 4, 4, 2) f32
// attw:  (2, 19947, 8, 4, 4) f32 ; out: (2, 19947, 256) f32
// R3: value transposed to (b,h,key,32ch) f16; (b,h) pinned to XCD via
// pair = blk & 15 (XCD = blk % 8) -> 2.56 MB L2 set; row-pair 128B loads.
// R4: packed-fp16 accumulation; x-weight via distance form max(0,1-|x-k|).
// R7: asm-forced gather pipeline -- counted s_waitcnt vmcnt(N) +
// sched_barrier(0), 3-buffer rotation, 16-24 loads in flight.
// R10: lane-dedup addr math + __shfl broadcast.  (Best: 84.5 us)
// R13: revert R12 (dup layout broke the 4MB/XCD L2 budget: FETCH 56->150MB);
// transpose grid pinned so pair p stages on XCD p%8 (same as gather) -> L2
// pre-warm of the pair's value pyramid.
// LESSON (R9): keep launch_bounds loose; scratch spills corrupt manual vmcnt.
// LESSON (R11): not VALU-bound. LESSON (R12): footprint <= 2MB/pair or L2 dies.

#define KQ 19947
#define NBQ (2 * KQ)

// ---------- transpose + convert: (b,k,h,32) f32 -> (b*8+h, k, 32) f16 ----------
// grid (16, ceil(KQ*4/256)): pair = blockIdx.x -> flat%8 = pair%8 = gather XCD.
__global__ __launch_bounds__(256) void transpose_f16(
    const float* __restrict__ V, __half* __restrict__ Vh)
{
    const int pair = blockIdx.x;                    // b*8+h
    const int j = blockIdx.y * 256 + threadIdx.x;   // (k, cg) flat, cg = 8ch group
    if (j >= KQ * 4) return;
    const int k = j >> 2, cg = j & 3;
    const int b = pair >> 3, h = pair & 7;
    const float* src = V + (((size_t)b * KQ + k) * 8 + h) * 32 + cg * 8;
    const float4 a0 = *reinterpret_cast<const float4*>(src);
    const float4 a1 = *reinterpret_cast<const float4*>(src + 4);
    __half2 h0 = __floats2half2_rn(a0.x, a0.y);
    __half2 h1 = __floats2half2_rn(a0.z, a0.w);
    __half2 h2 = __floats2half2_rn(a1.x, a1.y);
    __half2 h3 = __floats2half2_rn(a1.z, a1.w);
    uint4 o;
    o.x = *reinterpret_cast<unsigned int*>(&h0);
    o.y = *reinterpret_cast<unsigned int*>(&h1);
    o.z = *reinterpret_cast<unsigned int*>(&h2);
    o.w = *reinterpret_cast<unsigned int*>(&h3);
    reinterpret_cast<uint4*>(Vh + ((size_t)pair * KQ) * 32)[j] = o;
}

// Shared (slot-invariant) math for one sample point. Lane j handles point
// pt = j + 8*ROUND; level = 2*ROUND + (j>>2), p = j&3.
template<int ROUND>
static __device__ __forceinline__ void shared_point(
    int j, float2 g, float w,
    int& offb0, int& offb1, float& dxx, float& wy0w, float& wy1w)
{
    const bool hi = (j & 4) != 0;
    const int Wl = (ROUND == 0) ? (hi ? 75 : 150) : (hi ? 19 : 38);
    const int Hl = (ROUND == 0) ? (hi ? 50 : 100) : (hi ? 13 : 25);
    const int st = (ROUND == 0) ? (hi ? 15000 : 0) : (hi ? 19700 : 18750);
    const float Wf = (float)Wl, Hf = (float)Hl;
    const float x = fmaf(g.x, Wf, -0.5f);
    const float y = fmaf(g.y, Hf, -0.5f);
    const float fy = floorf(y);
    const int y0 = (int)fy;
    const int x0 = (int)floorf(x);
    // x0 in [-1, W-1]; bx in [0, W-2] -> keys bx, bx+1 distinct, in bounds.
    const int bx = min(max(x0, 0), Wl - 2);
    dxx = x - (float)bx;                 // consumer: wxl = max(0,1-|dxx-slot|)
    const float wy1 = y - fy, wy0 = 1.f - wy1;
    const int y0c = max(y0, 0);
    const int y1c = min(y0 + 1, Hl - 1);
    const float ay0 = (y0 >= 0) ? wy0 : 0.f;
    const float ay1 = (y0 + 1 < Hl) ? wy1 : 0.f;
    wy0w = w * ay0;
    wy1w = w * ay1;
    offb0 = (st + y0c * Wl + bx) << 5;   // half-elem offset, lane base in vbl
    offb1 = (st + y1c * Wl + bx) << 5;
}

static __device__ __forceinline__ void consume_level(
    const uint4* v, const float* cw, float acc[8])
{
    __half2 accH[4];
    #pragma unroll
    for (int j = 0; j < 4; ++j) accH[j] = __half2(__half(0.f), __half(0.f));
    #pragma unroll
    for (int i = 0; i < 8; ++i) {
        const __half2 wh = __floats2half2_rn(cw[i], cw[i]);
        union { uint4 u; __half2 h2[4]; } uv;
        uv.u = v[i];
        #pragma unroll
        for (int j = 0; j < 4; ++j)
            accH[j] = __hfma2(wh, uv.h2[j], accH[j]);
    }
    #pragma unroll
    for (int j = 0; j < 4; ++j) {
        const float2 f = __half22float2(accH[j]);
        acc[2*j]   += f.x;
        acc[2*j+1] += f.y;
    }
}

#define GLOAD8(buf, obase)                                                   \
    {                                                                        \
        _Pragma("unroll")                                                    \
        for (int i = 0; i < 8; ++i) {                                        \
            const __half* p_ = vbl + (obase)[i];                             \
            asm volatile("global_load_dwordx4 %0, %1, off"                   \
                         : "=v"(buf[i]) : "v"(p_));                          \
        }                                                                    \
    }
#define VWAIT(n)                                                             \
    asm volatile("s_waitcnt vmcnt(" #n ")" ::: "memory");                    \
    __builtin_amdgcn_sched_barrier(0)
#define SBAR() __builtin_amdgcn_sched_barrier(0)

// ---------- gather: block = one (b,h) x 32 queries; 8 lanes per query ----------
__global__ __launch_bounds__(256, 3) void msda_fwd_t(
    const __half* __restrict__ Vh,
    const float* __restrict__ LOC,
    const float* __restrict__ W,
    float* __restrict__ OUT)
{
    const int pair = blockIdx.x & 15;               // b*8+h -> XCD = blk % 8
    const int qc   = blockIdx.x >> 4;
    const int tid  = threadIdx.x;
    const int s    = tid & 7;                       // slot = s>>2, chgrp = s&3
    const int slot = s >> 2;
    const float slotf = (float)slot;
    const int q    = qc * 32 + (tid >> 3);
    if (q >= KQ) return;
    const int b = pair >> 3, h = pair & 7;
    const int ln = tid & 63;                        // lane in wave
    const int gb = ln & 56;                         // query-group base lane

    // lane base: + s*8 halves covers [key base+slot, channels chgrp*8..+8)
    const __half* vbl = Vh + (size_t)pair * KQ * 32 + s * 8;
    const float* lp = LOC + (((size_t)b * KQ + q) * 8 + h) * 32;
    const float* wp = W   + (((size_t)b * KQ + q) * 8 + h) * 16;

    float acc[8];
    #pragma unroll
    for (int c = 0; c < 8; ++c) acc[c] = 0.f;

    // ---- dedup addr math: lane j computes points j and j+8 once ----
    const float2 gA = *reinterpret_cast<const float2*>(lp + 2 * s);
    const float  wA = wp[s];
    const float2 gB = *reinterpret_cast<const float2*>(lp + 2 * s + 16);
    const float  wB = wp[s + 8];

    int ob0A, ob1A, ob0B, ob1B;
    float dxA, u0A, u1A, dxB, u0B, u1B;
    shared_point<0>(s, gA, wA, ob0A, ob1A, dxA, u0A, u1A);
    shared_point<1>(s, gB, wB, ob0B, ob1B, dxB, u0B, u1B);

    // ---- broadcast + per-slot finish: off/cw for all 16 points ----
    int off[32];
    float cw[32];
    #pragma unroll
    for (int pt = 0; pt < 8; ++pt) {                // points 0..7 (levels 0,1)
        const int src = gb + pt;
        const int   o0 = __shfl(ob0A, src, 64);
        const int   o1 = __shfl(ob1A, src, 64);
        const float dx = __shfl(dxA,  src, 64);
        const float u0 = __shfl(u0A,  src, 64);
        const float u1 = __shfl(u1A,  src, 64);
        const float wxl = fmaxf(0.f, 1.f - fabsf(dx - slotf));
        off[2*pt]   = o0;
        off[2*pt+1] = o1;
        cw[2*pt]    = u0 * wxl;
        cw[2*pt+1]  = u1 * wxl;
    }
    #pragma unroll
    for (int pt = 0; pt < 8; ++pt) {                // points 8..15 (levels 2,3)
        const int src = gb + pt;
        const int   o0 = __shfl(ob0B, src, 64);
        const int   o1 = __shfl(ob1B, src, 64);
        const float dx = __shfl(dxB,  src, 64);
        const float u0 = __shfl(u0B,  src, 64);
        const float u1 = __shfl(u1B,  src, 64);
        const float wxl = fmaxf(0.f, 1.f - fabsf(dx - slotf));
        off[16+2*pt]   = o0;
        off[16+2*pt+1] = o1;
        cw[16+2*pt]    = u0 * wxl;
        cw[16+2*pt+1]  = u1 * wxl;
    }

    // drain compiler-issued vmem (loc/attw) so manual vmcnt counts are exact
    VWAIT(0);

    uint4 va[8], vb2[8], vc[8];
    GLOAD8(va,  off + 0);                 // l0: 8 outstanding
    GLOAD8(vb2, off + 8);                 // l1: 16 outstanding
    VWAIT(8);                             // l0 ready
    GLOAD8(vc,  off + 16);                // l2: 16 outstanding
    SBAR();
    consume_level(va, cw + 0, acc);       // level 0
    SBAR();                               // pin consume before va reuse
    GLOAD8(va,  off + 24);                // l3: <= 24 outstanding
    VWAIT(16);                            // l1 ready (l2, l3 in flight)
    consume_level(vb2, cw + 8, acc);      // level 1
    VWAIT(8);                             // l2 ready
    consume_level(vc, cw + 16, acc);      // level 2
    VWAIT(0);                             // l3 ready
    consume_level(va, cw + 24, acc);      // level 3

    // combine the two key-slots: lanes s and s^4 hold the two x-corners
    #pragma unroll
    for (int c = 0; c < 8; ++c)
        acc[c] += __shfl_xor(acc[c], 4, 64);

    // lane s writes channels chgrp*8 + slot*4 .. +4  (values acc[slot*4..+4))
    float* op = OUT + ((size_t)b * KQ + q) * 256 + h * 32 + (s & 3) * 8 + slot * 4;
    *reinterpret_cast<float4*>(op) =
        make_float4(acc[slot*4], acc[slot*4+1], acc[slot*4+2], acc[slot*4+3]);
}

// ---------- f32 fallback (no workspace needed) ----------
static __device__ __forceinline__ void fmadd4(float4& a, float s, const float4 v) {
    a.x = fmaf(s, v.x, a.x);
    a.y = fmaf(s, v.y, a.y);
    a.z = fmaf(s, v.z, a.z);
    a.w = fmaf(s, v.w, a.w);
}

__global__ __launch_bounds__(256, 4) void msda_fwd_f32(
    const float* __restrict__ V,
    const float* __restrict__ LOC,
    const float* __restrict__ W,
    float* __restrict__ OUT)
{
    const int t  = blockIdx.x * 256 + threadIdx.x;
    const int cg = t & 7;
    const int h  = (t >> 3) & 7;
    const int bq = t >> 6;
    if (bq >= NBQ) return;
    const int b = (bq >= KQ) ? 1 : 0;

    const int Hs[4]  = {100, 50, 25, 13};
    const int Ws[4]  = {150, 75, 38, 19};
    const int STs[4] = {0, 15000, 18750, 19700};

    const int hoff = (h << 5) + (cg << 2);
    const float* vb = V + (size_t)b * KQ * 256 + hoff;
    const float* lp = LOC + ((size_t)bq * 8 + h) * 32;
    const float* wp = W   + ((size_t)bq * 8 + h) * 16;

    float4 acc = make_float4(0.f, 0.f, 0.f, 0.f);

    #pragma unroll
    for (int l = 0; l < 4; ++l) {
        const int Hh = Hs[l], Ww = Ws[l], st = STs[l];
        const float Hf = (float)Hh, Wf = (float)Ww;
        const float4 w4 = *reinterpret_cast<const float4*>(wp + l * 4);
        const float4 g0 = *reinterpret_cast<const float4*>(lp + l * 8);
        const float4 g1 = *reinterpret_cast<const float4*>(lp + l * 8 + 4);
        const float lx[4] = {g0.x, g0.z, g1.x, g1.z};
        const float ly[4] = {g0.y, g0.w, g1.y, g1.w};
        const float ww[4] = {w4.x, w4.y, w4.z, w4.w};
        #pragma unroll
        for (int p = 0; p < 4; ++p) {
            const float x = fmaf(lx[p], Wf, -0.5f);
            const float y = fmaf(ly[p], Hf, -0.5f);
            const float fx = floorf(x), fy = floorf(y);
            const int x0 = (int)fx, y0 = (int)fy;
            const float wx1 = x - fx, wy1 = y - fy;
            const float wx0 = 1.f - wx1, wy0 = 1.f - wy1;
            const int x0c = max(x0, 0),     x1c = min(x0 + 1, Ww - 1);
            const int y0c = max(y0, 0),     y1c = min(y0 + 1, Hh - 1);
            const float ax0 = (x0 >= 0)      ? wx0 : 0.f;
            const float ax1 = (x0 + 1 < Ww)  ? wx1 : 0.f;
            const float ay0 = (y0 >= 0)      ? wy0 : 0.f;
            const float ay1 = (y0 + 1 < Hh)  ? wy1 : 0.f;
            const float w = ww[p];
            const int b0 = st + y0c * Ww, b1 = st + y1c * Ww;
            fmadd4(acc, w*ay0*ax0, *reinterpret_cast<const float4*>(vb + ((b0+x0c) << 8)));
            fmadd4(acc, w*ay0*ax1, *reinterpret_cast<const float4*>(vb + ((b0+x1c) << 8)));
            fmadd4(acc, w*ay1*ax0, *reinterpret_cast<const float4*>(vb + ((b1+x0c) << 8)));
            fmadd4(acc, w*ay1*ax1, *reinterpret_cast<const float4*>(vb + ((b1+x1c) << 8)));
        }
    }
    *reinterpret_cast<float4*>(OUT + (size_t)bq * 256 + hoff) = acc;
}

extern "C" void kernel_launch(void* const* d_in, const int* in_sizes, int n_in,
                              void* d_out, int out_size, void* d_ws, size_t ws_size,
                              hipStream_t stream) {
    const float* V   = (const float*)d_in[0];
    const float* LOC = (const float*)d_in[2];
    const float* W   = (const float*)d_in[3];
    float* OUT = (float*)d_out;

    const size_t n_val = (size_t)2 * KQ * 256;          // 10,212,864 halves
    const size_t need  = n_val * sizeof(__half) + 256;  // ~20.4 MB

    if (ws_size >= need) {
        __half* Vh = (__half*)d_ws;
        const int jtot = KQ * 4;                        // (k, cg) per pair
        // grid (16, jblocks): flat id % 8 == pair % 8 -> same XCD as gather
        dim3 tgrid(16, (jtot + 255) / 256);
        hipLaunchKernelGGL(transpose_f16, tgrid, dim3(256), 0, stream, V, Vh);

        const int qchunks = (KQ + 31) / 32;             // 624
        const int blocks  = qchunks * 16;               // 9984
        hipLaunchKernelGGL(msda_fwd_t, dim3(blocks), dim3(256), 0, stream,
                           Vh, LOC, W, OUT);
    } else {
        const int total = NBQ * 64;
        hipLaunchKernelGGL(msda_fwd_f32, dim3((total + 255) / 256), dim3(256), 0, stream,
                           V, LOC, W, OUT);
    }
}

// Round 15
// 83.459 us; speedup vs baseline: 1.2756x; 1.0092x over previous
//
#include <hip/hip_runtime.h>
#include <hip/hip_fp16.h>

// Multi-scale deformable attention forward, MI355X.
// value: (2, 19947, 8, 32) f32 ; loc: (2, 19947, 8, 4, 4, 2) f32
// attw:  (2, 19947, 8, 4, 4) f32 ; out: (2, 19947, 256) f32
// R3: value transposed per (b,h); pair pinned to XCD (pair = blk & 15).
// R4: packed-fp16 accumulation; x-weight via distance form max(0,1-|x-k|).
// R7: asm gather pipeline, counted vmcnt + sched_barrier, 16-24 in flight.
// R10: lane-dedup addr math + __shfl broadcast. (84.2 us)
// R14: capacity-SAFE x-pair dup: levels 1-3 stored as 128B-aligned dup
// entries [key x | key x+1] (every row access = 1 line, was 1.5); level 0
// stays plain. Pair footprint 1.58 MB x2 = 3.16 MB < 4 MB L2 (R12's dup-l0
// blew capacity at 2.46 MB/pair). Lines/query 48 -> 36 (-25%).
// LESSON (R9): loose launch_bounds; scratch spills corrupt manual vmcnt.
// LESSON (R11): not VALU-bound. LESSON (R12): footprint budget is 2MB/pair.

#define KQ 19947
#define NBQ (2 * KQ)

// dup2 layout, units = halves, per pair:
//   L0 plain @ 0      : 15000 keys x 32            = 480000
//   L1 dup   @ 480000 : 50 rows x 74 entries x 64  = 236800
//   L2 dup   @ 716800 : 25 rows x 37 entries x 64  =  59200
//   L3 dup   @ 776000 : 13 rows x 18 entries x 64  =  14976
#define PAIR_H2 790976

// ---------- pack 8 f32 -> 8 f16 (16B) ----------
static __device__ __forceinline__ uint4 pack8(const float* __restrict__ src) {
    const float4 a0 = *reinterpret_cast<const float4*>(src);
    const float4 a1 = *reinterpret_cast<const float4*>(src + 4);
    __half2 h0 = __floats2half2_rn(a0.x, a0.y);
    __half2 h1 = __floats2half2_rn(a0.z, a0.w);
    __half2 h2 = __floats2half2_rn(a1.x, a1.y);
    __half2 h3 = __floats2half2_rn(a1.z, a1.w);
    uint4 o;
    o.x = *reinterpret_cast<unsigned int*>(&h0);
    o.y = *reinterpret_cast<unsigned int*>(&h1);
    o.z = *reinterpret_cast<unsigned int*>(&h2);
    o.w = *reinterpret_cast<unsigned int*>(&h3);
    return o;
}

// ---------- transpose variants (grid (16, j): pair -> XCD pair%8) ----------
__global__ __launch_bounds__(256) void transpose_f16(
    const float* __restrict__ V, __half* __restrict__ Vh)
{
    const int pair = blockIdx.x;
    const int j = blockIdx.y * 256 + threadIdx.x;
    if (j >= KQ * 4) return;
    const int k = j >> 2, cg = j & 3;
    const int b = pair >> 3, h = pair & 7;
    const uint4 o = pack8(V + (((size_t)b * KQ + k) * 8 + h) * 32 + cg * 8);
    reinterpret_cast<uint4*>(Vh + ((size_t)pair * KQ) * 32)[j] = o;
}

__global__ __launch_bounds__(256) void transpose_dup2(
    const float* __restrict__ V, __half* __restrict__ Vh)
{
    const int pair = blockIdx.x;
    const int j = blockIdx.y * 256 + threadIdx.x;
    if (j >= KQ * 4) return;
    const int k = j >> 2, cg = j & 3;
    const int b = pair >> 3, h = pair & 7;
    const uint4 o = pack8(V + (((size_t)b * KQ + k) * 8 + h) * 32 + cg * 8);
    __half* base = Vh + (size_t)pair * PAIR_H2;
    int dst0 = -1, dst1 = -1;                       // in halves
    if (k < 15000) {                                // level 0 plain
        dst0 = k * 32 + cg * 8;
    } else if (k < 18750) {                         // level 1 dup: 50 x 75
        const int kk = k - 15000;
        const int y = kk / 75, x = kk - y * 75;
        if (x <= 73) dst0 = 480000 + (y * 74 + x) * 64 + cg * 8;
        if (x >= 1)  dst1 = 480000 + (y * 74 + x - 1) * 64 + 32 + cg * 8;
    } else if (k < 19700) {                         // level 2 dup: 25 x 38
        const int kk = k - 18750;
        const int y = kk / 38, x = kk - y * 38;
        if (x <= 36) dst0 = 716800 + (y * 37 + x) * 64 + cg * 8;
        if (x >= 1)  dst1 = 716800 + (y * 37 + x - 1) * 64 + 32 + cg * 8;
    } else {                                        // level 3 dup: 13 x 19
        const int kk = k - 19700;
        const int y = kk / 19, x = kk - y * 19;
        if (x <= 17) dst0 = 776000 + (y * 18 + x) * 64 + cg * 8;
        if (x >= 1)  dst1 = 776000 + (y * 18 + x - 1) * 64 + 32 + cg * 8;
    }
    if (dst0 >= 0) *reinterpret_cast<uint4*>(base + dst0) = o;
    if (dst1 >= 0) *reinterpret_cast<uint4*>(base + dst1) = o;
}

// ---------- shared (slot-invariant) point math ----------
// Lane j handles point pt = j + 8*ROUND; level = 2*ROUND + (j>>2).
template<int ROUND, bool DUP>
static __device__ __forceinline__ void shared_point(
    int j, float2 g, float w,
    int& offb0, int& offb1, float& dxx, float& wy0w, float& wy1w)
{
    const bool hi = (j & 4) != 0;
    const int Wl = (ROUND == 0) ? (hi ? 75 : 150) : (hi ? 19 : 38);
    const int Hl = (ROUND == 0) ? (hi ? 50 : 100) : (hi ? 13 : 25);
    const float Wf = (float)Wl, Hf = (float)Hl;
    const float x = fmaf(g.x, Wf, -0.5f);
    const float y = fmaf(g.y, Hf, -0.5f);
    const float fy = floorf(y);
    const int y0 = (int)fy;
    const int x0 = (int)floorf(x);
    const int bx = min(max(x0, 0), Wl - 2);
    dxx = x - (float)bx;                 // consumer: wxl = max(0,1-|dxx-slot|)
    const float wy1 = y - fy, wy0 = 1.f - wy1;
    const int y0c = max(y0, 0);
    const int y1c = min(y0 + 1, Hl - 1);
    const float ay0 = (y0 >= 0) ? wy0 : 0.f;
    const float ay1 = (y0 + 1 < Hl) ? wy1 : 0.f;
    wy0w = w * ay0;
    wy1w = w * ay1;
    if (DUP) {
        if (ROUND == 0 && !hi) {         // level 0 plain: key idx * 32
            offb0 = (y0c * 150 + bx) << 5;
            offb1 = (y1c * 150 + bx) << 5;
        } else {                         // dup entry: (y*(W-1)+bx) * 64
            const int stride = Wl - 1;
            const int baseH = (ROUND == 0) ? 480000 : (hi ? 776000 : 716800);
            offb0 = baseH + ((y0c * stride + bx) << 6);
            offb1 = baseH + ((y1c * stride + bx) << 6);
        }
    } else {
        const int st = (ROUND == 0) ? (hi ? 15000 : 0) : (hi ? 19700 : 18750);
        offb0 = (st + y0c * Wl + bx) << 5;
        offb1 = (st + y1c * Wl + bx) << 5;
    }
}

static __device__ __forceinline__ void consume_level(
    const uint4* v, const float* cw, float acc[8])
{
    __half2 accH[4];
    #pragma unroll
    for (int j = 0; j < 4; ++j) accH[j] = __half2(__half(0.f), __half(0.f));
    #pragma unroll
    for (int i = 0; i < 8; ++i) {
        const __half2 wh = __floats2half2_rn(cw[i], cw[i]);
        union { uint4 u; __half2 h2[4]; } uv;
        uv.u = v[i];
        #pragma unroll
        for (int j = 0; j < 4; ++j)
            accH[j] = __hfma2(wh, uv.h2[j], accH[j]);
    }
    #pragma unroll
    for (int j = 0; j < 4; ++j) {
        const float2 f = __half22float2(accH[j]);
        acc[2*j]   += f.x;
        acc[2*j+1] += f.y;
    }
}

#define GLOAD8(buf, obase)                                                   \
    {                                                                        \
        _Pragma("unroll")                                                    \
        for (int i = 0; i < 8; ++i) {                                        \
            const __half* p_ = vbl + (obase)[i];                             \
            asm volatile("global_load_dwordx4 %0, %1, off"                   \
                         : "=v"(buf[i]) : "v"(p_));                          \
        }                                                                    \
    }
#define VWAIT(n)                                                             \
    asm volatile("s_waitcnt vmcnt(" #n ")" ::: "memory");                    \
    __builtin_amdgcn_sched_barrier(0)
#define SBAR() __builtin_amdgcn_sched_barrier(0)

// ---------- gather: block = one (b,h) x 32 queries; 8 lanes per query ----------
template<bool DUP>
__global__ __launch_bounds__(256, 3) void msda_fwd_t(
    const __half* __restrict__ Vh,
    const float* __restrict__ LOC,
    const float* __restrict__ W,
    float* __restrict__ OUT)
{
    const int pair = blockIdx.x & 15;               // b*8+h -> XCD = blk % 8
    const int qc   = blockIdx.x >> 4;
    const int tid  = threadIdx.x;
    const int s    = tid & 7;                       // slot = s>>2, chgrp = s&3
    const int slot = s >> 2;
    const float slotf = (float)slot;
    const int q    = qc * 32 + (tid >> 3);
    if (q >= KQ) return;
    const int b = pair >> 3, h = pair & 7;
    const int ln = tid & 63;
    const int gb = ln & 56;                         // query-group base lane

    const size_t pairBase = DUP ? ((size_t)pair * PAIR_H2)
                                : ((size_t)pair * KQ * 32);
    const __half* vbl = Vh + pairBase + s * 8;
    const float* lp = LOC + (((size_t)b * KQ + q) * 8 + h) * 32;
    const float* wp = W   + (((size_t)b * KQ + q) * 8 + h) * 16;

    float acc[8];
    #pragma unroll
    for (int c = 0; c < 8; ++c) acc[c] = 0.f;

    // ---- dedup addr math: lane j computes points j and j+8 once ----
    const float2 gA = *reinterpret_cast<const float2*>(lp + 2 * s);
    const float  wA = wp[s];
    const float2 gB = *reinterpret_cast<const float2*>(lp + 2 * s + 16);
    const float  wB = wp[s + 8];

    int ob0A, ob1A, ob0B, ob1B;
    float dxA, u0A, u1A, dxB, u0B, u1B;
    shared_point<0, DUP>(s, gA, wA, ob0A, ob1A, dxA, u0A, u1A);
    shared_point<1, DUP>(s, gB, wB, ob0B, ob1B, dxB, u0B, u1B);

    // ---- broadcast + per-slot finish: off/cw for all 16 points ----
    int off[32];
    float cw[32];
    #pragma unroll
    for (int pt = 0; pt < 8; ++pt) {                // points 0..7 (levels 0,1)
        const int src = gb + pt;
        const int   o0 = __shfl(ob0A, src, 64);
        const int   o1 = __shfl(ob1A, src, 64);
        const float dx = __shfl(dxA,  src, 64);
        const float u0 = __shfl(u0A,  src, 64);
        const float u1 = __shfl(u1A,  src, 64);
        const float wxl = fmaxf(0.f, 1.f - fabsf(dx - slotf));
        off[2*pt]   = o0;
        off[2*pt+1] = o1;
        cw[2*pt]    = u0 * wxl;
        cw[2*pt+1]  = u1 * wxl;
    }
    #pragma unroll
    for (int pt = 0; pt < 8; ++pt) {                // points 8..15 (levels 2,3)
        const int src = gb + pt;
        const int   o0 = __shfl(ob0B, src, 64);
        const int   o1 = __shfl(ob1B, src, 64);
        const float dx = __shfl(dxB,  src, 64);
        const float u0 = __shfl(u0B,  src, 64);
        const float u1 = __shfl(u1B,  src, 64);
        const float wxl = fmaxf(0.f, 1.f - fabsf(dx - slotf));
        off[16+2*pt]   = o0;
        off[16+2*pt+1] = o1;
        cw[16+2*pt]    = u0 * wxl;
        cw[16+2*pt+1]  = u1 * wxl;
    }

    // drain compiler-issued vmem (loc/attw) so manual vmcnt counts are exact
    VWAIT(0);

    uint4 va[8], vb2[8], vc[8];
    GLOAD8(va,  off + 0);                 // l0: 8 outstanding
    GLOAD8(vb2, off + 8);                 // l1: 16 outstanding
    VWAIT(8);                             // l0 ready
    GLOAD8(vc,  off + 16);                // l2: 16 outstanding
    SBAR();
    consume_level(va, cw + 0, acc);       // level 0
    SBAR();                               // pin consume before va reuse
    GLOAD8(va,  off + 24);                // l3: <= 24 outstanding
    VWAIT(16);                            // l1 ready (l2, l3 in flight)
    consume_level(vb2, cw + 8, acc);      // level 1
    VWAIT(8);                             // l2 ready
    consume_level(vc, cw + 16, acc);      // level 2
    VWAIT(0);                             // l3 ready
    consume_level(va, cw + 24, acc);      // level 3

    // combine the two key-slots: lanes s and s^4 hold the two x-corners
    #pragma unroll
    for (int c = 0; c < 8; ++c)
        acc[c] += __shfl_xor(acc[c], 4, 64);

    // lane s writes channels chgrp*8 + slot*4 .. +4
    float* op = OUT + ((size_t)b * KQ + q) * 256 + h * 32 + (s & 3) * 8 + slot * 4;
    *reinterpret_cast<float4*>(op) =
        make_float4(acc[slot*4], acc[slot*4+1], acc[slot*4+2], acc[slot*4+3]);
}

// ---------- f32 fallback (no workspace needed) ----------
static __device__ __forceinline__ void fmadd4(float4& a, float s, const float4 v) {
    a.x = fmaf(s, v.x, a.x);
    a.y = fmaf(s, v.y, a.y);
    a.z = fmaf(s, v.z, a.z);
    a.w = fmaf(s, v.w, a.w);
}

__global__ __launch_bounds__(256, 4) void msda_fwd_f32(
    const float* __restrict__ V,
    const float* __restrict__ LOC,
    const float* __restrict__ W,
    float* __restrict__ OUT)
{
    const int t  = blockIdx.x * 256 + threadIdx.x;
    const int cg = t & 7;
    const int h  = (t >> 3) & 7;
    const int bq = t >> 6;
    if (bq >= NBQ) return;
    const int b = (bq >= KQ) ? 1 : 0;

    const int Hs[4]  = {100, 50, 25, 13};
    const int Ws[4]  = {150, 75, 38, 19};
    const int STs[4] = {0, 15000, 18750, 19700};

    const int hoff = (h << 5) + (cg << 2);
    const float* vb = V + (size_t)b * KQ * 256 + hoff;
    const float* lp = LOC + ((size_t)bq * 8 + h) * 32;
    const float* wp = W   + ((size_t)bq * 8 + h) * 16;

    float4 acc = make_float4(0.f, 0.f, 0.f, 0.f);

    #pragma unroll
    for (int l = 0; l < 4; ++l) {
        const int Hh = Hs[l], Ww = Ws[l], st = STs[l];
        const float Hf = (float)Hh, Wf = (float)Ww;
        const float4 w4 = *reinterpret_cast<const float4*>(wp + l * 4);
        const float4 g0 = *reinterpret_cast<const float4*>(lp + l * 8);
        const float4 g1 = *reinterpret_cast<const float4*>(lp + l * 8 + 4);
        const float lx[4] = {g0.x, g0.z, g1.x, g1.z};
        const float ly[4] = {g0.y, g0.w, g1.y, g1.w};
        const float ww[4] = {w4.x, w4.y, w4.z, w4.w};
        #pragma unroll
        for (int p = 0; p < 4; ++p) {
            const float x = fmaf(lx[p], Wf, -0.5f);
            const float y = fmaf(ly[p], Hf, -0.5f);
            const float fx = floorf(x), fy = floorf(y);
            const int x0 = (int)fx, y0 = (int)fy;
            const float wx1 = x - fx, wy1 = y - fy;
            const float wx0 = 1.f - wx1, wy0 = 1.f - wy1;
            const int x0c = max(x0, 0),     x1c = min(x0 + 1, Ww - 1);
            const int y0c = max(y0, 0),     y1c = min(y0 + 1, Hh - 1);
            const float ax0 = (x0 >= 0)      ? wx0 : 0.f;
            const float ax1 = (x0 + 1 < Ww)  ? wx1 : 0.f;
            const float ay0 = (y0 >= 0)      ? wy0 : 0.f;
            const float ay1 = (y0 + 1 < Hh)  ? wy1 : 0.f;
            const float w = ww[p];
            const int b0 = st + y0c * Ww, b1 = st + y1c * Ww;
            fmadd4(acc, w*ay0*ax0, *reinterpret_cast<const float4*>(vb + ((b0+x0c) << 8)));
            fmadd4(acc, w*ay0*ax1, *reinterpret_cast<const float4*>(vb + ((b0+x1c) << 8)));
            fmadd4(acc, w*ay1*ax0, *reinterpret_cast<const float4*>(vb + ((b1+x0c) << 8)));
            fmadd4(acc, w*ay1*ax1, *reinterpret_cast<const float4*>(vb + ((b1+x1c) << 8)));
        }
    }
    *reinterpret_cast<float4*>(OUT + (size_t)bq * 256 + hoff) = acc;
}

extern "C" void kernel_launch(void* const* d_in, const int* in_sizes, int n_in,
                              void* d_out, int out_size, void* d_ws, size_t ws_size,
                              hipStream_t stream) {
    const float* V   = (const float*)d_in[0];
    const float* LOC = (const float*)d_in[2];
    const float* W   = (const float*)d_in[3];
    float* OUT = (float*)d_out;

    const size_t need_dup2  = (size_t)16 * PAIR_H2 * 2 + 256;      // ~25.3 MB
    const size_t need_plain = (size_t)2 * KQ * 256 * 2 + 256;      // ~20.4 MB
    const int jtot = KQ * 4;
    const int qchunks = (KQ + 31) / 32;             // 624
    const int gblocks = qchunks * 16;               // 9984
    dim3 tgrid(16, (jtot + 255) / 256);             // pair -> XCD pair%8

    if (ws_size >= need_dup2) {
        __half* Vh = (__half*)d_ws;
        hipLaunchKernelGGL(transpose_dup2, tgrid, dim3(256), 0, stream, V, Vh);
        hipLaunchKernelGGL((msda_fwd_t<true>), dim3(gblocks), dim3(256), 0, stream,
                           Vh, LOC, W, OUT);
    } else if (ws_size >= need_plain) {
        __half* Vh = (__half*)d_ws;
        hipLaunchKernelGGL(transpose_f16, tgrid, dim3(256), 0, stream, V, Vh);
        hipLaunchKernelGGL((msda_fwd_t<false>), dim3(gblocks), dim3(256), 0, stream,
                           Vh, LOC, W, OUT);
    } else {
        const int total = NBQ * 64;
        hipLaunchKernelGGL(msda_fwd_f32, dim3((total + 255) / 256), dim3(256), 0, stream,
                           V, LOC, W, OUT);
    }
}